// Round 16
// baseline (64.529 us; speedup 1.0000x reference)
//
#include <hip/hip_runtime.h>
#include <hip/hip_bf16.h>
#include <stdint.h>

// ---------------------------------------------------------------------------
// MultiScaleAttention: x[4,128,4096] -> 3x conv1x1+PReLU -> attention -> out
//   conv (fused transpose): Q [n][s][64] bf16 (*log2e), K/V in MFMA-fragment-
//   ready GLOBAL layouts (1KB contiguous per wave-fragment -> linear LDS
//   staging, zero bank conflicts). Split-bf16 MFMA for fp32-level accuracy.
//   attn: q=64/wave (q=256/block), KVBLK=32, 4-buffer LDS, distance-3
//   counted-vmcnt pipeline: ONE raw s_barrier per region preceded by
//   s_waitcnt vmcnt(6) (tiles t+1,t+2 stay in flight); vmcnt(3)/(0) only in
//   the last two tiles. No setprio (ablated neutral, R15).
//   p = exp2(S^T) unnormalized; num bf16 + den f32 partials over 8 kv-splits.
// KF layout: [n][t(32k)][d0(4)][slot(64)]*16B, slot=hi*32+l31 ->
//            K[t*32+l31][d0*16+hi*8 ..+8]
// VF layout: [n][t(32k)][dvb*2+kc(8)][slot(64)]*16B, slot=hi*32+l31 ->
//            V^T[dvb*32+l31][t*32+kc*16+hi*8 ..+8]
// ---------------------------------------------------------------------------

typedef float   f32x16 __attribute__((ext_vector_type(16)));
typedef __bf16  bf16x8 __attribute__((ext_vector_type(8)));
typedef __bf16  bf16x2 __attribute__((ext_vector_type(2)));
typedef unsigned int u32x4 __attribute__((ext_vector_type(4)));
typedef unsigned int u32x2 __attribute__((ext_vector_type(2)));

#define L2E 1.4426950408889634f

// workspace layout (bytes); ws_size ~268MB
#define Q_OFF   (0u)                          // [4][4096][64] bf16 = 2MB
#define KF_OFF  (2u << 20)                    // frag-K, 512KB/batch = 2MB
#define VF_OFF  (4u << 20)                    // frag-V, 1MB/batch = 4MB
#define DEN_OFF (8u << 20)                    // [4][16][8][256] f32 = 512KB
#define WH_OFF  ((8u << 20) + (1u << 19))     // W hi bf16 [256][128] = 64KB
#define WL_OFF  (WH_OFF + (1u << 16))
#define OP_OFF  (9u << 20)                    // num bf16 [4][16][8][128][256] = 33.5MB

__device__ inline unsigned short f2bf(float f) {   // hw v_cvt (RNE)
  __bf16 h = (__bf16)f;
  return __builtin_bit_cast(unsigned short, h);
}
__device__ inline float bf2f(unsigned short h) {
  unsigned u = ((unsigned)h) << 16;
  return __builtin_bit_cast(float, u);
}
__device__ inline unsigned pack2(float a, float b) {   // v_cvt_pk_bf16_f32
  bf16x2 t = { (__bf16)a, (__bf16)b };
  return __builtin_bit_cast(unsigned, t);
}

__device__ inline void gld_lds16(const void* g, void* l) {
  __builtin_amdgcn_global_load_lds(
      (const __attribute__((address_space(1))) unsigned*)g,
      (__attribute__((address_space(3))) unsigned*)l, 16, 0, 0);
}

// --------------------------- kernel 0: cast weights ------------------------
__global__ void wcast_kernel(const float* __restrict__ w1, const float* __restrict__ w2,
                             const float* __restrict__ wa, char* __restrict__ ws) {
  int idx = blockIdx.x * 256 + threadIdx.x;   // 32 blocks
  unsigned short* WH = (unsigned short*)(ws + WH_OFF);
  unsigned short* WL = (unsigned short*)(ws + WL_OFF);
#pragma unroll
  for (int r = 0; r < 4; ++r) {
    int i = r * 8192 + idx;                   // 0..32767
    int oc = i >> 7, c = i & 127;
    float v = oc < 64 ? w1[oc * 128 + c]
            : (oc < 128 ? w2[(oc - 64) * 128 + c] : wa[(oc - 128) * 128 + c]);
    __bf16 h = (__bf16)v;
    WH[i] = __builtin_bit_cast(unsigned short, h);
    WL[i] = f2bf(v - (float)h);
  }
}

// ------- kernel 1: conv1x1 + bias + PReLU -> Q, KF, VF (fused transpose) ----
// 512 blocks = 4n * 128 s-tiles(32). Waves: 0->Q(*L2E), 1->K, 2,3->V.
__global__ __launch_bounds__(256) void conv_kernel(
    const float* __restrict__ x, char* __restrict__ ws,
    const float* __restrict__ b1, const float* __restrict__ a1,
    const float* __restrict__ b2, const float* __restrict__ a2,
    const float* __restrict__ ba, const float* __restrict__ aa) {
  int bid = blockIdx.x;
  int n = bid >> 7, st = bid & 127;           // st == kv tile index t
  int sb = st * 32;
  int tid = threadIdx.x;
  int wid = tid >> 6, lane = tid & 63, l31 = lane & 31, hi = lane >> 5;

  __shared__ float xl[128][36];         // x-tile transpose; later reused as vl
  __shared__ float tl[2][64][33];       // Q/K f32 transpose buffers
  float* vl = (float*)xl;               // [128][33] V f32, reuse after MFMA

  const float* xb = x + (size_t)n * 128 * 4096;
#pragma unroll
  for (int it = 0; it < 4; ++it) {      // load 128x32 f32 tile
    int flat4 = tid + 256 * it;
    int c = flat4 >> 3, s4 = flat4 & 7;
    float4 v = *(const float4*)(xb + (size_t)c * 4096 + sb + s4 * 4);
    *(float4*)&xl[c][s4 * 4] = v;
  }
  __syncthreads();

  const char* WH = ws + WH_OFF;
  const char* WL = ws + WL_OFF;
  int oc0 = wid * 64;

  f32x16 acc[2];
  acc[0] = 0.f; acc[1] = 0.f;
#pragma unroll
  for (int c0 = 0; c0 < 8; ++c0) {
    __bf16 eh[8], el[8];
#pragma unroll
    for (int j = 0; j < 8; ++j) {
      float v = xl[c0 * 16 + hi * 8 + j][l31];
      __bf16 h = (__bf16)v;
      eh[j] = h;
      el[j] = (__bf16)(v - (float)h);
    }
    bf16x8 xh = {eh[0], eh[1], eh[2], eh[3], eh[4], eh[5], eh[6], eh[7]};
    bf16x8 xlo = {el[0], el[1], el[2], el[3], el[4], el[5], el[6], el[7]};
#pragma unroll
    for (int mb = 0; mb < 2; ++mb) {
      size_t wo = (size_t)(oc0 + mb * 32 + l31) * 256 + c0 * 32 + hi * 16;
      bf16x8 wh = *(const bf16x8*)(WH + wo);
      bf16x8 wl = *(const bf16x8*)(WL + wo);
      acc[mb] = __builtin_amdgcn_mfma_f32_32x32x16_bf16(wh, xh, acc[mb], 0, 0, 0);
      acc[mb] = __builtin_amdgcn_mfma_f32_32x32x16_bf16(wh, xlo, acc[mb], 0, 0, 0);
      acc[mb] = __builtin_amdgcn_mfma_f32_32x32x16_bf16(wl, xh, acc[mb], 0, 0, 0);
    }
  }
  __syncthreads();                      // all waves done reading xl

  if (wid < 2) {
    const float* bb = wid ? b2 : b1;
    float slope = wid ? a2[0] : a1[0];
    float scl = wid ? 1.0f : L2E;       // fold softmax log2e into Q
#pragma unroll
    for (int mb = 0; mb < 2; ++mb)
#pragma unroll
      for (int reg = 0; reg < 16; ++reg) {
        int row = mb * 32 + (reg & 3) + 8 * (reg >> 2) + 4 * hi;
        float y = acc[mb][reg] + bb[row];
        y = fmaxf(y, 0.f) + slope * fminf(y, 0.f);
        tl[wid][row][l31] = y * scl;
      }
  } else {
    float slope = aa[0];
#pragma unroll
    for (int mb = 0; mb < 2; ++mb)
#pragma unroll
      for (int reg = 0; reg < 16; ++reg) {
        int dv = (wid - 2) * 64 + mb * 32 + (reg & 3) + 8 * (reg >> 2) + 4 * hi;
        float y = acc[mb][reg] + ba[dv];
        y = fmaxf(y, 0.f) + slope * fminf(y, 0.f);
        vl[dv * 33 + l31] = y;
      }
  }
  __syncthreads();

  if (wid == 0) {                       // Q natural [s][64] bf16
    char* Qg = ws + Q_OFF + (size_t)n * (4096 * 128);
#pragma unroll
    for (int it = 0; it < 4; ++it) {
      int sl = (lane >> 3) + it * 8;
      u32x4 pv;
#pragma unroll
      for (int p = 0; p < 4; ++p)
        pv[p] = pack2(tl[0][(lane & 7) * 8 + 2 * p][sl],
                      tl[0][(lane & 7) * 8 + 2 * p + 1][sl]);
      *(u32x4*)(Qg + (size_t)(sb + sl) * 128 + (lane & 7) * 16) = pv;
    }
  } else if (wid == 1) {                // K fragment layout
    char* KFb = ws + KF_OFF + (size_t)n * (512 << 10);
    int d0 = (lane & 7) >> 1, hs = lane & 1;
#pragma unroll
    for (int it = 0; it < 4; ++it) {
      int sl = (lane >> 3) + it * 8;
      u32x4 pv;
#pragma unroll
      for (int p = 0; p < 4; ++p)
        pv[p] = pack2(tl[1][(lane & 7) * 8 + 2 * p][sl],
                      tl[1][(lane & 7) * 8 + 2 * p + 1][sl]);
      *(u32x4*)(KFb + ((size_t)(st * 4 + d0) * 64 + hs * 32 + sl) * 16) = pv;
    }
  }
  // all 256 threads: V fragment stores (512 units of 16B)
  {
    char* VFb = ws + VF_OFF + (size_t)n * (1u << 20);
#pragma unroll
    for (int r = 0; r < 2; ++r) {
      int u = tid + r * 256;
      int dv = u >> 2, sc = u & 3;
      u32x4 pv;
#pragma unroll
      for (int p = 0; p < 4; ++p)
        pv[p] = pack2(vl[dv * 33 + sc * 8 + 2 * p], vl[dv * 33 + sc * 8 + 2 * p + 1]);
      int unit = st * 8 + (dv >> 5) * 2 + (sc >> 1);
      *(u32x4*)(VFb + ((size_t)unit * 64 + (sc & 1) * 32 + (dv & 31)) * 16) = pv;
    }
  }
}

// --------------------------- kernel 2: flash attention ----------------------
// 512 blocks: bid = ((batch*16+qt)<<3)|split -> split==XCD (bid%8).
// Block = 4 waves * 64 q = 256 q; kv = split*512..+512 (16 tiles of 32).
// 4-buffer LDS (48KB), stage distance 3; region:
//   {s_waitcnt vmcnt(6); s_barrier; stage(t+3); QK(t)+SM(t)+PV(t)}
// -> tiles t+1 AND t+2's staging loads stay in flight across the barrier.
__global__ __launch_bounds__(256, 2) void attn_kernel(char* __restrict__ ws) {
  int bid = blockIdx.x;
  int split = bid & 7;
  int qt = (bid >> 3) & 15;
  int batch = bid >> 7;
  int tid = threadIdx.x;
  int wid = tid >> 6, lane = tid & 63, l31 = lane & 31, hi = lane >> 5;

  const char* Qb  = ws + Q_OFF  + (size_t)batch * (4096 * 128);
  const char* Kt0 = ws + KF_OFF + (size_t)batch * (512 << 10) +
                    (size_t)(split * 16) * 4096;
  const char* Vt0 = ws + VF_OFF + (size_t)batch * (1u << 20) +
                    (size_t)(split * 16) * 8192;

  __shared__ char sbuf[4][12288];       // [0,4K)=K tile, [4K,12K)=V tile

  int q0 = qt * 256 + wid * 64;
  int lo16 = lane * 16;

  bf16x8 qf0[4], qf1[4];                // Q frags for the wave's 2 q-sets
#pragma unroll
  for (int d0 = 0; d0 < 4; ++d0) {
    qf0[d0] = *(const bf16x8*)(Qb + (size_t)(q0 + l31) * 128 + d0 * 32 + hi * 16);
    qf1[d0] = *(const bf16x8*)(Qb + (size_t)(q0 + 32 + l31) * 128 + d0 * 32 + hi * 16);
  }

  f32x16 oacc[2][4];
#pragma unroll
  for (int qs = 0; qs < 2; ++qs)
#pragma unroll
    for (int i = 0; i < 4; ++i) oacc[qs][i] = 0.f;
  float denA0 = 0.f, denA1 = 0.f, denB0 = 0.f, denB1 = 0.f;

  // each wave stages 3 of the 12 1KB chunks (K: c<4, V: c>=4)
  auto stage = [&](int b, int t) {
#pragma unroll
    for (int i = 0; i < 3; ++i) {
      int c = wid * 3 + i;
      const char* src = (c < 4) ? Kt0 + (size_t)t * 4096 + c * 1024 + lo16
                                : Vt0 + (size_t)t * 8192 + (c - 4) * 1024 + lo16;
      gld_lds16(src, &sbuf[b][c * 1024]);
    }
  };

  stage(0, 0);                          // 3 outstanding (this wave)
  stage(1, 1);                          // 6 outstanding
  stage(2, 2);                          // 9 outstanding

  for (int t = 0; t < 16; ++t) {
    // wait ONLY for tile t's 3 loads (issued 3 regions ago); t+1/t+2 in flight
    if (t < 14)      asm volatile("s_waitcnt vmcnt(6)" ::: "memory");
    else if (t < 15) asm volatile("s_waitcnt vmcnt(3)" ::: "memory");
    else             asm volatile("s_waitcnt vmcnt(0)" ::: "memory");
    __builtin_amdgcn_s_barrier();       // raw: no drain; all waves' chunks in

    if (t + 3 < 16) stage((t + 3) & 3, t + 3);   // overlaps this region

    const char* kb = sbuf[t & 3];
    const char* vb = kb + 4096;

    // QK both q-sets: S^T[k][q], k = (reg&3)+8*(reg>>2)+4*hi, q = l31
    f32x16 s0, s1;
    s0 = 0.f; s1 = 0.f;
#pragma unroll
    for (int d0 = 0; d0 < 4; ++d0) {
      bf16x8 kf = *(const bf16x8*)(kb + d0 * 1024 + lo16);
      s0 = __builtin_amdgcn_mfma_f32_32x32x16_bf16(kf, qf0[d0], s0, 0, 0, 0);
      s1 = __builtin_amdgcn_mfma_f32_32x32x16_bf16(kf, qf1[d0], s1, 0, 0, 0);
    }

    // softmax: p = exp2(s) (Q pre-scaled by log2e), unnormalized
    unsigned pk0[8], pk1[8];
#pragma unroll
    for (int m = 0; m < 8; ++m) {
      float a0 = __builtin_amdgcn_exp2f(s0[2 * m]);
      float a1 = __builtin_amdgcn_exp2f(s0[2 * m + 1]);
      if (m & 1) denA1 += a0 + a1; else denA0 += a0 + a1;
      pk0[m] = pack2(a0, a1);
      float b0 = __builtin_amdgcn_exp2f(s1[2 * m]);
      float b1 = __builtin_amdgcn_exp2f(s1[2 * m + 1]);
      if (m & 1) denB1 += b0 + b1; else denB0 += b0 + b1;
      pk1[m] = pack2(b0, b1);
    }

    // PV: O^T[dv][q] += V^T · P^T ; each vf read feeds both q-sets
#pragma unroll
    for (int kc = 0; kc < 2; ++kc) {
      const int bs = kc * 4;
      u32x2 r0 = __builtin_amdgcn_permlane32_swap(pk0[bs + 0], pk0[bs + 2],
                                                  false, false);
      u32x2 r1 = __builtin_amdgcn_permlane32_swap(pk0[bs + 1], pk0[bs + 3],
                                                  false, false);
      u32x4 pu0 = {r0.x, r1.x, r0.y, r1.y};
      bf16x8 pf0 = __builtin_bit_cast(bf16x8, pu0);
      u32x2 r2 = __builtin_amdgcn_permlane32_swap(pk1[bs + 0], pk1[bs + 2],
                                                  false, false);
      u32x2 r3 = __builtin_amdgcn_permlane32_swap(pk1[bs + 1], pk1[bs + 3],
                                                  false, false);
      u32x4 pu1 = {r2.x, r3.x, r2.y, r3.y};
      bf16x8 pf1 = __builtin_bit_cast(bf16x8, pu1);
#pragma unroll
      for (int dvb = 0; dvb < 4; ++dvb) {
        bf16x8 vf = *(const bf16x8*)(vb + (dvb * 2 + kc) * 1024 + lo16);
        oacc[0][dvb] = __builtin_amdgcn_mfma_f32_32x32x16_bf16(vf, pf0,
                                                               oacc[0][dvb], 0, 0, 0);
        oacc[1][dvb] = __builtin_amdgcn_mfma_f32_32x32x16_bf16(vf, pf1,
                                                               oacc[1][dvb], 0, 0, 0);
      }
    }
    // no trailing barrier: next region's top barrier provides WAR safety
    // (buffer (t+3)&3 was last read at region t-1, two barriers ago)
  }

  // write numerator partials (bf16, cacheable -> L2/L3 for combine) + den
  unsigned short* OPu = (unsigned short*)(ws + OP_OFF) +
                        (size_t)((batch * 16 + qt) * 8 + split) * 32768;
#pragma unroll
  for (int qs = 0; qs < 2; ++qs) {
    int qloc = wid * 64 + qs * 32 + l31;
#pragma unroll
    for (int dvb = 0; dvb < 4; ++dvb)
#pragma unroll
      for (int reg = 0; reg < 16; ++reg) {
        int dv = dvb * 32 + (reg & 3) + 8 * (reg >> 2) + 4 * hi;
        OPu[dv * 256 + qloc] = f2bf(oacc[qs][dvb][reg]);
      }
    float den = qs ? (denB0 + denB1) : (denA0 + denA1);
    float dtot = den + __shfl_xor(den, 32, 64);
    if (hi == 0) {
      float* DEN = (float*)(ws + DEN_OFF) +
                   (size_t)((batch * 16 + qt) * 8 + split) * 256;
      DEN[qloc] = dtot;
    }
  }
}

// --------------------------- kernel 3: combine splits -----------------------
// 1024 blocks; each thread produces 8 consecutive outputs (vectorized loads).
__global__ __launch_bounds__(256) void combine_kernel(const char* __restrict__ ws,
                                                      float* __restrict__ out) {
  int idx8 = (blockIdx.x * 256 + threadIdx.x) * 8;  // 2^21 outputs [n][c][s]
  int n = idx8 >> 19;
  int dv = (idx8 >> 12) & 127;
  int s0 = idx8 & 4095;                 // 8-aligned
  int qt = s0 >> 8, ql = s0 & 255;
  const unsigned short* OPu = (const unsigned short*)(ws + OP_OFF);
  const float* DEN = (const float*)(ws + DEN_OFF);
  size_t pb = (size_t)((n * 16 + qt) * 8);
  float num[8], den[8];
#pragma unroll
  for (int j = 0; j < 8; ++j) { num[j] = 0.f; den[j] = 0.f; }
#pragma unroll
  for (int h = 0; h < 8; ++h) {
    bf16x8 v = *(const bf16x8*)(OPu + (pb + h) * 32768 + (size_t)dv * 256 + ql);
    const float* dp = DEN + (pb + h) * 256 + ql;
    float4 d0 = *(const float4*)dp;
    float4 d1 = *(const float4*)(dp + 4);
#pragma unroll
    for (int j = 0; j < 8; ++j) num[j] += (float)v[j];
    den[0] += d0.x; den[1] += d0.y; den[2] += d0.z; den[3] += d0.w;
    den[4] += d1.x; den[5] += d1.y; den[6] += d1.z; den[7] += d1.w;
  }
  float4 o0 = {num[0] / den[0], num[1] / den[1], num[2] / den[2], num[3] / den[3]};
  float4 o1 = {num[4] / den[4], num[5] / den[5], num[6] / den[6], num[7] / den[7]};
  *(float4*)&out[idx8] = o0;
  *(float4*)&out[idx8 + 4] = o1;
}

// ---------------------------------------------------------------------------
extern "C" void kernel_launch(void* const* d_in, const int* in_sizes, int n_in,
                              void* d_out, int out_size, void* d_ws, size_t ws_size,
                              hipStream_t stream) {
  (void)in_sizes; (void)n_in; (void)out_size; (void)ws_size;
  const float* x  = (const float*)d_in[0];
  const float* w1 = (const float*)d_in[1];
  const float* b1 = (const float*)d_in[2];
  const float* a1 = (const float*)d_in[3];
  const float* w2 = (const float*)d_in[4];
  const float* b2 = (const float*)d_in[5];
  const float* a2 = (const float*)d_in[6];
  const float* wa = (const float*)d_in[7];
  const float* ba = (const float*)d_in[8];
  const float* aa = (const float*)d_in[9];
  char* ws = (char*)d_ws;
  float* out = (float*)d_out;

  wcast_kernel<<<dim3(32), dim3(256), 0, stream>>>(w1, w2, wa, ws);
  conv_kernel<<<dim3(512), dim3(256), 0, stream>>>(x, ws, b1, a1, b2, a2, ba, aa);
  attn_kernel<<<dim3(512), dim3(256), 0, stream>>>(ws);
  combine_kernel<<<dim3(1024), dim3(256), 0, stream>>>(ws, out);
}

// Round 17
// 64.215 us; speedup vs baseline: 1.0049x; 1.0049x over previous
//
#include <hip/hip_runtime.h>
#include <hip/hip_bf16.h>
#include <stdint.h>

// ---------------------------------------------------------------------------
// MultiScaleAttention: x[4,128,4096] -> 3x conv1x1+PReLU -> attention -> out
//   conv: B-fragments (x^T) read DIRECTLY from global (coalesced per (c,j);
//   4x L1 reuse across waves) -- no x staging, one barrier. Split-bf16 MFMA.
//   Q [n][s][64] bf16 (*log2e); K/V in MFMA-fragment-ready GLOBAL layouts
//   (1KB contiguous per wave-fragment -> linear LDS staging, zero conflicts).
//   attn (R13-exact): q=64/wave (q=256/block), KVBLK=32, 3-buffer LDS,
//   counted-vmcnt: ONE raw s_barrier per region preceded by s_waitcnt
//   vmcnt(3); vmcnt(0) only at the last tile; setprio around MFMA clusters.
//   p = exp2(S^T) unnormalized; num bf16 + den f32 partials over 8 kv-splits.
// KF layout: [n][t(32k)][d0(4)][slot(64)]*16B, slot=hi*32+l31 ->
//            K[t*32+l31][d0*16+hi*8 ..+8]
// VF layout: [n][t(32k)][dvb*2+kc(8)][slot(64)]*16B, slot=hi*32+l31 ->
//            V^T[dvb*32+l31][t*32+kc*16+hi*8 ..+8]
// ---------------------------------------------------------------------------

typedef float   f32x16 __attribute__((ext_vector_type(16)));
typedef __bf16  bf16x8 __attribute__((ext_vector_type(8)));
typedef __bf16  bf16x2 __attribute__((ext_vector_type(2)));
typedef unsigned int u32x4 __attribute__((ext_vector_type(4)));
typedef unsigned int u32x2 __attribute__((ext_vector_type(2)));

#define L2E 1.4426950408889634f

// workspace layout (bytes); ws_size ~268MB
#define Q_OFF   (0u)                          // [4][4096][64] bf16 = 2MB
#define KF_OFF  (2u << 20)                    // frag-K, 512KB/batch = 2MB
#define VF_OFF  (4u << 20)                    // frag-V, 1MB/batch = 4MB
#define DEN_OFF (8u << 20)                    // [4][16][8][256] f32 = 512KB
#define WH_OFF  ((8u << 20) + (1u << 19))     // W hi bf16 [256][128] = 64KB
#define WL_OFF  (WH_OFF + (1u << 16))
#define OP_OFF  (9u << 20)                    // num bf16 [4][16][8][128][256] = 33.5MB

__device__ inline unsigned short f2bf(float f) {   // hw v_cvt (RNE)
  __bf16 h = (__bf16)f;
  return __builtin_bit_cast(unsigned short, h);
}
__device__ inline float bf2f(unsigned short h) {
  unsigned u = ((unsigned)h) << 16;
  return __builtin_bit_cast(float, u);
}
__device__ inline unsigned pack2(float a, float b) {   // v_cvt_pk_bf16_f32
  bf16x2 t = { (__bf16)a, (__bf16)b };
  return __builtin_bit_cast(unsigned, t);
}

__device__ inline void gld_lds16(const void* g, void* l) {
  __builtin_amdgcn_global_load_lds(
      (const __attribute__((address_space(1))) unsigned*)g,
      (__attribute__((address_space(3))) unsigned*)l, 16, 0, 0);
}

// --------------------------- kernel 0: cast weights ------------------------
__global__ void wcast_kernel(const float* __restrict__ w1, const float* __restrict__ w2,
                             const float* __restrict__ wa, char* __restrict__ ws) {
  int idx = blockIdx.x * 256 + threadIdx.x;   // 32 blocks
  unsigned short* WH = (unsigned short*)(ws + WH_OFF);
  unsigned short* WL = (unsigned short*)(ws + WL_OFF);
#pragma unroll
  for (int r = 0; r < 4; ++r) {
    int i = r * 8192 + idx;                   // 0..32767
    int oc = i >> 7, c = i & 127;
    float v = oc < 64 ? w1[oc * 128 + c]
            : (oc < 128 ? w2[(oc - 64) * 128 + c] : wa[(oc - 128) * 128 + c]);
    __bf16 h = (__bf16)v;
    WH[i] = __builtin_bit_cast(unsigned short, h);
    WL[i] = f2bf(v - (float)h);
  }
}

// ------- kernel 1: conv1x1 + bias + PReLU -> Q, KF, VF ----------------------
// 512 blocks = 4n * 128 s-tiles(32). Waves: 0->Q(*L2E), 1->K, 2,3->V.
// B-frags read directly from global x (coalesced; L1-shared across waves).
__global__ __launch_bounds__(256) void conv_kernel(
    const float* __restrict__ x, char* __restrict__ ws,
    const float* __restrict__ b1, const float* __restrict__ a1,
    const float* __restrict__ b2, const float* __restrict__ a2,
    const float* __restrict__ ba, const float* __restrict__ aa) {
  int bid = blockIdx.x;
  int n = bid >> 7, st = bid & 127;           // st == kv tile index t
  int sb = st * 32;
  int tid = threadIdx.x;
  int wid = tid >> 6, lane = tid & 63, l31 = lane & 31, hi = lane >> 5;

  __shared__ float tl[2][64][33];       // Q/K f32 transpose buffers
  __shared__ float vl[128 * 33];        // V f32 buffer

  const float* xb = x + (size_t)n * 128 * 4096;
  const char* WH = ws + WH_OFF;
  const char* WL = ws + WL_OFF;
  int oc0 = wid * 64;

  f32x16 acc[2];
  acc[0] = 0.f; acc[1] = 0.f;
#pragma unroll
  for (int c0 = 0; c0 < 8; ++c0) {
    // B-frag: x^T[s=sb+l31][k = c0*16 + hi*8 + j] straight from global
    float xv[8];
#pragma unroll
    for (int j = 0; j < 8; ++j)
      xv[j] = xb[(size_t)(c0 * 16 + hi * 8 + j) * 4096 + sb + l31];
    __bf16 eh[8], el[8];
#pragma unroll
    for (int j = 0; j < 8; ++j) {
      __bf16 h = (__bf16)xv[j];
      eh[j] = h;
      el[j] = (__bf16)(xv[j] - (float)h);
    }
    bf16x8 xh = {eh[0], eh[1], eh[2], eh[3], eh[4], eh[5], eh[6], eh[7]};
    bf16x8 xlo = {el[0], el[1], el[2], el[3], el[4], el[5], el[6], el[7]};
#pragma unroll
    for (int mb = 0; mb < 2; ++mb) {
      size_t wo = (size_t)(oc0 + mb * 32 + l31) * 256 + c0 * 32 + hi * 16;
      bf16x8 wh = *(const bf16x8*)(WH + wo);
      bf16x8 wl = *(const bf16x8*)(WL + wo);
      acc[mb] = __builtin_amdgcn_mfma_f32_32x32x16_bf16(wh, xh, acc[mb], 0, 0, 0);
      acc[mb] = __builtin_amdgcn_mfma_f32_32x32x16_bf16(wh, xlo, acc[mb], 0, 0, 0);
      acc[mb] = __builtin_amdgcn_mfma_f32_32x32x16_bf16(wl, xh, acc[mb], 0, 0, 0);
    }
  }

  if (wid < 2) {
    const float* bb = wid ? b2 : b1;
    float slope = wid ? a2[0] : a1[0];
    float scl = wid ? 1.0f : L2E;       // fold softmax log2e into Q
#pragma unroll
    for (int mb = 0; mb < 2; ++mb)
#pragma unroll
      for (int reg = 0; reg < 16; ++reg) {
        int row = mb * 32 + (reg & 3) + 8 * (reg >> 2) + 4 * hi;
        float y = acc[mb][reg] + bb[row];
        y = fmaxf(y, 0.f) + slope * fminf(y, 0.f);
        tl[wid][row][l31] = y * scl;
      }
  } else {
    float slope = aa[0];
#pragma unroll
    for (int mb = 0; mb < 2; ++mb)
#pragma unroll
      for (int reg = 0; reg < 16; ++reg) {
        int dv = (wid - 2) * 64 + mb * 32 + (reg & 3) + 8 * (reg >> 2) + 4 * hi;
        float y = acc[mb][reg] + ba[dv];
        y = fmaxf(y, 0.f) + slope * fminf(y, 0.f);
        vl[dv * 33 + l31] = y;
      }
  }

  if (wid == 0) {                       // Q natural [s][64] bf16 (same-wave tl)
    char* Qg = ws + Q_OFF + (size_t)n * (4096 * 128);
#pragma unroll
    for (int it = 0; it < 4; ++it) {
      int sl = (lane >> 3) + it * 8;
      u32x4 pv;
#pragma unroll
      for (int p = 0; p < 4; ++p)
        pv[p] = pack2(tl[0][(lane & 7) * 8 + 2 * p][sl],
                      tl[0][(lane & 7) * 8 + 2 * p + 1][sl]);
      *(u32x4*)(Qg + (size_t)(sb + sl) * 128 + (lane & 7) * 16) = pv;
    }
  } else if (wid == 1) {                // K fragment layout (same-wave tl)
    char* KFb = ws + KF_OFF + (size_t)n * (512 << 10);
    int d0 = (lane & 7) >> 1, hs = lane & 1;
#pragma unroll
    for (int it = 0; it < 4; ++it) {
      int sl = (lane >> 3) + it * 8;
      u32x4 pv;
#pragma unroll
      for (int p = 0; p < 4; ++p)
        pv[p] = pack2(tl[1][(lane & 7) * 8 + 2 * p][sl],
                      tl[1][(lane & 7) * 8 + 2 * p + 1][sl]);
      *(u32x4*)(KFb + ((size_t)(st * 4 + d0) * 64 + hs * 32 + sl) * 16) = pv;
    }
  }
  __syncthreads();                      // vl (waves 2,3) ready for all threads
  // all 256 threads: V fragment stores (512 units of 16B)
  {
    char* VFb = ws + VF_OFF + (size_t)n * (1u << 20);
#pragma unroll
    for (int r = 0; r < 2; ++r) {
      int u = tid + r * 256;
      int dv = u >> 2, sc = u & 3;
      u32x4 pv;
#pragma unroll
      for (int p = 0; p < 4; ++p)
        pv[p] = pack2(vl[dv * 33 + sc * 8 + 2 * p], vl[dv * 33 + sc * 8 + 2 * p + 1]);
      int unit = st * 8 + (dv >> 5) * 2 + (sc >> 1);
      *(u32x4*)(VFb + ((size_t)unit * 64 + (sc & 1) * 32 + (dv & 31)) * 16) = pv;
    }
  }
}

// --------------------------- kernel 2: flash attention ----------------------
// 512 blocks: bid = ((batch*16+qt)<<3)|split -> split==XCD (bid%8).
// Block = 4 waves * 64 q = 256 q; kv = split*512..+512 (16 tiles of 32).
// 3-buffer LDS (36KB), stage distance 2; region:
//   {s_waitcnt vmcnt(3); s_barrier; stage(t+2); QK(t)+SM(t)+PV(t)}
// -> tile t+1's staging loads remain in flight across the barrier (T4).
__global__ __launch_bounds__(256, 2) void attn_kernel(char* __restrict__ ws) {
  int bid = blockIdx.x;
  int split = bid & 7;
  int qt = (bid >> 3) & 15;
  int batch = bid >> 7;
  int tid = threadIdx.x;
  int wid = tid >> 6, lane = tid & 63, l31 = lane & 31, hi = lane >> 5;

  const char* Qb  = ws + Q_OFF  + (size_t)batch * (4096 * 128);
  const char* Kt0 = ws + KF_OFF + (size_t)batch * (512 << 10) +
                    (size_t)(split * 16) * 4096;
  const char* Vt0 = ws + VF_OFF + (size_t)batch * (1u << 20) +
                    (size_t)(split * 16) * 8192;

  __shared__ char sbuf[3][12288];       // [0,4K)=K tile, [4K,12K)=V tile

  int q0 = qt * 256 + wid * 64;
  int lo16 = lane * 16;

  bf16x8 qf0[4], qf1[4];                // Q frags for the wave's 2 q-sets
#pragma unroll
  for (int d0 = 0; d0 < 4; ++d0) {
    qf0[d0] = *(const bf16x8*)(Qb + (size_t)(q0 + l31) * 128 + d0 * 32 + hi * 16);
    qf1[d0] = *(const bf16x8*)(Qb + (size_t)(q0 + 32 + l31) * 128 + d0 * 32 + hi * 16);
  }

  f32x16 oacc[2][4];
#pragma unroll
  for (int qs = 0; qs < 2; ++qs)
#pragma unroll
    for (int i = 0; i < 4; ++i) oacc[qs][i] = 0.f;
  float denA0 = 0.f, denA1 = 0.f, denB0 = 0.f, denB1 = 0.f;

  // each wave stages 3 of the 12 1KB chunks (K: c<4, V: c>=4)
  auto stage = [&](int b, int t) {
#pragma unroll
    for (int i = 0; i < 3; ++i) {
      int c = wid * 3 + i;
      const char* src = (c < 4) ? Kt0 + (size_t)t * 4096 + c * 1024 + lo16
                                : Vt0 + (size_t)t * 8192 + (c - 4) * 1024 + lo16;
      gld_lds16(src, &sbuf[b][c * 1024]);
    }
  };

  stage(0, 0);                          // 3 outstanding (this wave)
  stage(1, 1);                          // 6 outstanding

  for (int t = 0; t < 16; ++t) {
    // wait ONLY for tile t's 3 loads (issued 2 regions ago); t+1's in flight
    if (t < 15) asm volatile("s_waitcnt vmcnt(3)" ::: "memory");
    else        asm volatile("s_waitcnt vmcnt(0)" ::: "memory");
    __builtin_amdgcn_s_barrier();       // raw: no drain; all waves' chunks in

    if (t + 2 < 16) stage((t + 2) % 3, t + 2);   // overlaps this region

    const char* kb = sbuf[t % 3];
    const char* vb = kb + 4096;

    // QK both q-sets: S^T[k][q], k = (reg&3)+8*(reg>>2)+4*hi, q = l31
    f32x16 s0, s1;
    s0 = 0.f; s1 = 0.f;
    __builtin_amdgcn_s_setprio(1);
#pragma unroll
    for (int d0 = 0; d0 < 4; ++d0) {
      bf16x8 kf = *(const bf16x8*)(kb + d0 * 1024 + lo16);
      s0 = __builtin_amdgcn_mfma_f32_32x32x16_bf16(kf, qf0[d0], s0, 0, 0, 0);
      s1 = __builtin_amdgcn_mfma_f32_32x32x16_bf16(kf, qf1[d0], s1, 0, 0, 0);
    }
    __builtin_amdgcn_s_setprio(0);

    // softmax: p = exp2(s) (Q pre-scaled by log2e), unnormalized
    unsigned pk0[8], pk1[8];
#pragma unroll
    for (int m = 0; m < 8; ++m) {
      float a0 = __builtin_amdgcn_exp2f(s0[2 * m]);
      float a1 = __builtin_amdgcn_exp2f(s0[2 * m + 1]);
      if (m & 1) denA1 += a0 + a1; else denA0 += a0 + a1;
      pk0[m] = pack2(a0, a1);
      float b0 = __builtin_amdgcn_exp2f(s1[2 * m]);
      float b1 = __builtin_amdgcn_exp2f(s1[2 * m + 1]);
      if (m & 1) denB1 += b0 + b1; else denB0 += b0 + b1;
      pk1[m] = pack2(b0, b1);
    }

    // PV: O^T[dv][q] += V^T · P^T ; each vf read feeds both q-sets
#pragma unroll
    for (int kc = 0; kc < 2; ++kc) {
      const int bs = kc * 4;
      u32x2 r0 = __builtin_amdgcn_permlane32_swap(pk0[bs + 0], pk0[bs + 2],
                                                  false, false);
      u32x2 r1 = __builtin_amdgcn_permlane32_swap(pk0[bs + 1], pk0[bs + 3],
                                                  false, false);
      u32x4 pu0 = {r0.x, r1.x, r0.y, r1.y};
      bf16x8 pf0 = __builtin_bit_cast(bf16x8, pu0);
      u32x2 r2 = __builtin_amdgcn_permlane32_swap(pk1[bs + 0], pk1[bs + 2],
                                                  false, false);
      u32x2 r3 = __builtin_amdgcn_permlane32_swap(pk1[bs + 1], pk1[bs + 3],
                                                  false, false);
      u32x4 pu1 = {r2.x, r3.x, r2.y, r3.y};
      bf16x8 pf1 = __builtin_bit_cast(bf16x8, pu1);
      __builtin_amdgcn_s_setprio(1);
#pragma unroll
      for (int dvb = 0; dvb < 4; ++dvb) {
        bf16x8 vf = *(const bf16x8*)(vb + (dvb * 2 + kc) * 1024 + lo16);
        oacc[0][dvb] = __builtin_amdgcn_mfma_f32_32x32x16_bf16(vf, pf0,
                                                               oacc[0][dvb], 0, 0, 0);
        oacc[1][dvb] = __builtin_amdgcn_mfma_f32_32x32x16_bf16(vf, pf1,
                                                               oacc[1][dvb], 0, 0, 0);
      }
      __builtin_amdgcn_s_setprio(0);
    }
    // no trailing barrier: next region's top barrier provides WAR safety
  }

  // write numerator partials (bf16, cacheable -> L2/L3 for combine) + den
  unsigned short* OPu = (unsigned short*)(ws + OP_OFF) +
                        (size_t)((batch * 16 + qt) * 8 + split) * 32768;
#pragma unroll
  for (int qs = 0; qs < 2; ++qs) {
    int qloc = wid * 64 + qs * 32 + l31;
#pragma unroll
    for (int dvb = 0; dvb < 4; ++dvb)
#pragma unroll
      for (int reg = 0; reg < 16; ++reg) {
        int dv = dvb * 32 + (reg & 3) + 8 * (reg >> 2) + 4 * hi;
        OPu[dv * 256 + qloc] = f2bf(oacc[qs][dvb][reg]);
      }
    float den = qs ? (denB0 + denB1) : (denA0 + denA1);
    float dtot = den + __shfl_xor(den, 32, 64);
    if (hi == 0) {
      float* DEN = (float*)(ws + DEN_OFF) +
                   (size_t)((batch * 16 + qt) * 8 + split) * 256;
      DEN[qloc] = dtot;
    }
  }
}

// --------------------------- kernel 3: combine splits -----------------------
// 1024 blocks; each thread produces 8 consecutive outputs (vectorized loads).
__global__ __launch_bounds__(256) void combine_kernel(const char* __restrict__ ws,
                                                      float* __restrict__ out) {
  int idx8 = (blockIdx.x * 256 + threadIdx.x) * 8;  // 2^21 outputs [n][c][s]
  int n = idx8 >> 19;
  int dv = (idx8 >> 12) & 127;
  int s0 = idx8 & 4095;                 // 8-aligned
  int qt = s0 >> 8, ql = s0 & 255;
  const unsigned short* OPu = (const unsigned short*)(ws + OP_OFF);
  const float* DEN = (const float*)(ws + DEN_OFF);
  size_t pb = (size_t)((n * 16 + qt) * 8);
  float num[8], den[8];
#pragma unroll
  for (int j = 0; j < 8; ++j) { num[j] = 0.f; den[j] = 0.f; }
#pragma unroll
  for (int h = 0; h < 8; ++h) {
    bf16x8 v = *(const bf16x8*)(OPu + (pb + h) * 32768 + (size_t)dv * 256 + ql);
    const float* dp = DEN + (pb + h) * 256 + ql;
    float4 d0 = *(const float4*)dp;
    float4 d1 = *(const float4*)(dp + 4);
#pragma unroll
    for (int j = 0; j < 8; ++j) num[j] += (float)v[j];
    den[0] += d0.x; den[1] += d0.y; den[2] += d0.z; den[3] += d0.w;
    den[4] += d1.x; den[5] += d1.y; den[6] += d1.z; den[7] += d1.w;
  }
  float4 o0 = {num[0] / den[0], num[1] / den[1], num[2] / den[2], num[3] / den[3]};
  float4 o1 = {num[4] / den[4], num[5] / den[5], num[6] / den[6], num[7] / den[7]};
  *(float4*)&out[idx8] = o0;
  *(float4*)&out[idx8 + 4] = o1;
}

// ---------------------------------------------------------------------------
extern "C" void kernel_launch(void* const* d_in, const int* in_sizes, int n_in,
                              void* d_out, int out_size, void* d_ws, size_t ws_size,
                              hipStream_t stream) {
  (void)in_sizes; (void)n_in; (void)out_size; (void)ws_size;
  const float* x  = (const float*)d_in[0];
  const float* w1 = (const float*)d_in[1];
  const float* b1 = (const float*)d_in[2];
  const float* a1 = (const float*)d_in[3];
  const float* w2 = (const float*)d_in[4];
  const float* b2 = (const float*)d_in[5];
  const float* a2 = (const float*)d_in[6];
  const float* wa = (const float*)d_in[7];
  const float* ba = (const float*)d_in[8];
  const float* aa = (const float*)d_in[9];
  char* ws = (char*)d_ws;
  float* out = (float*)d_out;

  wcast_kernel<<<dim3(32), dim3(256), 0, stream>>>(w1, w2, wa, ws);
  conv_kernel<<<dim3(512), dim3(256), 0, stream>>>(x, ws, b1, a1, b2, a2, ba, aa);
  attn_kernel<<<dim3(512), dim3(256), 0, stream>>>(ws);
  combine_kernel<<<dim3(1024), dim3(256), 0, stream>>>(ws, out);
}

// Round 18
// 59.201 us; speedup vs baseline: 1.0900x; 1.0847x over previous
//
#include <hip/hip_runtime.h>
#include <hip/hip_bf16.h>
#include <stdint.h>

// ---------------------------------------------------------------------------
// MultiScaleAttention: x[4,128,4096] -> 3x conv1x1+PReLU -> attention -> out
//   conv (fused transpose): Q [n][s][64] bf16 (*log2e), K/V in MFMA-fragment-
//   ready GLOBAL layouts (1KB contiguous per wave-fragment -> linear LDS
//   staging, zero bank conflicts). Split-bf16 MFMA for fp32-level accuracy.
//   attn: q=64/wave (q=256/block), KVBLK=32, 3-buffer LDS, T4 counted-vmcnt;
//   4 kv-splits (grid 256 = 1 block/CU; halves OP round-trip vs 8 splits).
//   p = exp2(S^T) unnormalized; num bf16 + den f32 partials; combine divides.
// KF layout: [n][t(32k)][d0(4)][slot(64)]*16B, slot=hi*32+l31 ->
//            K[t*32+l31][d0*16+hi*8 ..+8]
// VF layout: [n][t(32k)][dvb*2+kc(8)][slot(64)]*16B, slot=hi*32+l31 ->
//            V^T[dvb*32+l31][t*32+kc*16+hi*8 ..+8]
// ---------------------------------------------------------------------------

typedef float   f32x16 __attribute__((ext_vector_type(16)));
typedef __bf16  bf16x8 __attribute__((ext_vector_type(8)));
typedef __bf16  bf16x2 __attribute__((ext_vector_type(2)));
typedef unsigned int u32x4 __attribute__((ext_vector_type(4)));
typedef unsigned int u32x2 __attribute__((ext_vector_type(2)));

#define L2E 1.4426950408889634f

// workspace layout (bytes); ws_size ~268MB
#define Q_OFF   (0u)                          // [4][4096][64] bf16 = 2MB
#define KF_OFF  (2u << 20)                    // frag-K, 512KB/batch = 2MB
#define VF_OFF  (4u << 20)                    // frag-V, 1MB/batch = 4MB
#define DEN_OFF (8u << 20)                    // [4][16][4][256] f32 = 256KB
#define WH_OFF  ((8u << 20) + (1u << 19))     // W hi bf16 [256][128] = 64KB
#define WL_OFF  (WH_OFF + (1u << 16))
#define OP_OFF  (9u << 20)                    // num bf16 [4][16][4][128][256] = 16.8MB

__device__ inline unsigned short f2bf(float f) {   // hw v_cvt (RNE)
  __bf16 h = (__bf16)f;
  return __builtin_bit_cast(unsigned short, h);
}
__device__ inline float bf2f(unsigned short h) {
  unsigned u = ((unsigned)h) << 16;
  return __builtin_bit_cast(float, u);
}
__device__ inline unsigned pack2(float a, float b) {   // v_cvt_pk_bf16_f32
  bf16x2 t = { (__bf16)a, (__bf16)b };
  return __builtin_bit_cast(unsigned, t);
}

__device__ inline void gld_lds16(const void* g, void* l) {
  __builtin_amdgcn_global_load_lds(
      (const __attribute__((address_space(1))) unsigned*)g,
      (__attribute__((address_space(3))) unsigned*)l, 16, 0, 0);
}

// --------------------------- kernel 0: cast weights ------------------------
__global__ void wcast_kernel(const float* __restrict__ w1, const float* __restrict__ w2,
                             const float* __restrict__ wa, char* __restrict__ ws) {
  int idx = blockIdx.x * 256 + threadIdx.x;   // 32 blocks
  unsigned short* WH = (unsigned short*)(ws + WH_OFF);
  unsigned short* WL = (unsigned short*)(ws + WL_OFF);
#pragma unroll
  for (int r = 0; r < 4; ++r) {
    int i = r * 8192 + idx;                   // 0..32767
    int oc = i >> 7, c = i & 127;
    float v = oc < 64 ? w1[oc * 128 + c]
            : (oc < 128 ? w2[(oc - 64) * 128 + c] : wa[(oc - 128) * 128 + c]);
    __bf16 h = (__bf16)v;
    WH[i] = __builtin_bit_cast(unsigned short, h);
    WL[i] = f2bf(v - (float)h);
  }
}

// ------- kernel 1: conv1x1 + bias + PReLU -> Q, KF, VF (fused transpose) ----
// 512 blocks = 4n * 128 s-tiles(32). Waves: 0->Q(*L2E), 1->K, 2,3->V.
__global__ __launch_bounds__(256) void conv_kernel(
    const float* __restrict__ x, char* __restrict__ ws,
    const float* __restrict__ b1, const float* __restrict__ a1,
    const float* __restrict__ b2, const float* __restrict__ a2,
    const float* __restrict__ ba, const float* __restrict__ aa) {
  int bid = blockIdx.x;
  int n = bid >> 7, st = bid & 127;           // st == kv tile index t
  int sb = st * 32;
  int tid = threadIdx.x;
  int wid = tid >> 6, lane = tid & 63, l31 = lane & 31, hi = lane >> 5;

  __shared__ float xl[128][36];         // x-tile transpose; later reused as vl
  __shared__ float tl[2][64][33];       // Q/K f32 transpose buffers
  float* vl = (float*)xl;               // [128][33] V f32, reuse after MFMA

  const float* xb = x + (size_t)n * 128 * 4096;
#pragma unroll
  for (int it = 0; it < 4; ++it) {      // load 128x32 f32 tile
    int flat4 = tid + 256 * it;
    int c = flat4 >> 3, s4 = flat4 & 7;
    float4 v = *(const float4*)(xb + (size_t)c * 4096 + sb + s4 * 4);
    *(float4*)&xl[c][s4 * 4] = v;
  }
  __syncthreads();

  const char* WH = ws + WH_OFF;
  const char* WL = ws + WL_OFF;
  int oc0 = wid * 64;

  f32x16 acc[2];
  acc[0] = 0.f; acc[1] = 0.f;
#pragma unroll
  for (int c0 = 0; c0 < 8; ++c0) {
    __bf16 eh[8], el[8];
#pragma unroll
    for (int j = 0; j < 8; ++j) {
      float v = xl[c0 * 16 + hi * 8 + j][l31];
      __bf16 h = (__bf16)v;
      eh[j] = h;
      el[j] = (__bf16)(v - (float)h);
    }
    bf16x8 xh = {eh[0], eh[1], eh[2], eh[3], eh[4], eh[5], eh[6], eh[7]};
    bf16x8 xlo = {el[0], el[1], el[2], el[3], el[4], el[5], el[6], el[7]};
#pragma unroll
    for (int mb = 0; mb < 2; ++mb) {
      size_t wo = (size_t)(oc0 + mb * 32 + l31) * 256 + c0 * 32 + hi * 16;
      bf16x8 wh = *(const bf16x8*)(WH + wo);
      bf16x8 wl = *(const bf16x8*)(WL + wo);
      acc[mb] = __builtin_amdgcn_mfma_f32_32x32x16_bf16(wh, xh, acc[mb], 0, 0, 0);
      acc[mb] = __builtin_amdgcn_mfma_f32_32x32x16_bf16(wh, xlo, acc[mb], 0, 0, 0);
      acc[mb] = __builtin_amdgcn_mfma_f32_32x32x16_bf16(wl, xh, acc[mb], 0, 0, 0);
    }
  }
  __syncthreads();                      // all waves done reading xl

  if (wid < 2) {
    const float* bb = wid ? b2 : b1;
    float slope = wid ? a2[0] : a1[0];
    float scl = wid ? 1.0f : L2E;       // fold softmax log2e into Q
#pragma unroll
    for (int mb = 0; mb < 2; ++mb)
#pragma unroll
      for (int reg = 0; reg < 16; ++reg) {
        int row = mb * 32 + (reg & 3) + 8 * (reg >> 2) + 4 * hi;
        float y = acc[mb][reg] + bb[row];
        y = fmaxf(y, 0.f) + slope * fminf(y, 0.f);
        tl[wid][row][l31] = y * scl;
      }
  } else {
    float slope = aa[0];
#pragma unroll
    for (int mb = 0; mb < 2; ++mb)
#pragma unroll
      for (int reg = 0; reg < 16; ++reg) {
        int dv = (wid - 2) * 64 + mb * 32 + (reg & 3) + 8 * (reg >> 2) + 4 * hi;
        float y = acc[mb][reg] + ba[dv];
        y = fmaxf(y, 0.f) + slope * fminf(y, 0.f);
        vl[dv * 33 + l31] = y;
      }
  }
  __syncthreads();

  if (wid == 0) {                       // Q natural [s][64] bf16
    char* Qg = ws + Q_OFF + (size_t)n * (4096 * 128);
#pragma unroll
    for (int it = 0; it < 4; ++it) {
      int sl = (lane >> 3) + it * 8;
      u32x4 pv;
#pragma unroll
      for (int p = 0; p < 4; ++p)
        pv[p] = pack2(tl[0][(lane & 7) * 8 + 2 * p][sl],
                      tl[0][(lane & 7) * 8 + 2 * p + 1][sl]);
      *(u32x4*)(Qg + (size_t)(sb + sl) * 128 + (lane & 7) * 16) = pv;
    }
  } else if (wid == 1) {                // K fragment layout
    char* KFb = ws + KF_OFF + (size_t)n * (512 << 10);
    int d0 = (lane & 7) >> 1, hs = lane & 1;
#pragma unroll
    for (int it = 0; it < 4; ++it) {
      int sl = (lane >> 3) + it * 8;
      u32x4 pv;
#pragma unroll
      for (int p = 0; p < 4; ++p)
        pv[p] = pack2(tl[1][(lane & 7) * 8 + 2 * p][sl],
                      tl[1][(lane & 7) * 8 + 2 * p + 1][sl]);
      *(u32x4*)(KFb + ((size_t)(st * 4 + d0) * 64 + hs * 32 + sl) * 16) = pv;
    }
  }
  // all 256 threads: V fragment stores (512 units of 16B)
  {
    char* VFb = ws + VF_OFF + (size_t)n * (1u << 20);
#pragma unroll
    for (int r = 0; r < 2; ++r) {
      int u = tid + r * 256;
      int dv = u >> 2, sc = u & 3;
      u32x4 pv;
#pragma unroll
      for (int p = 0; p < 4; ++p)
        pv[p] = pack2(vl[dv * 33 + sc * 8 + 2 * p], vl[dv * 33 + sc * 8 + 2 * p + 1]);
      int unit = st * 8 + (dv >> 5) * 2 + (sc >> 1);
      *(u32x4*)(VFb + ((size_t)unit * 64 + (sc & 1) * 32 + (dv & 31)) * 16) = pv;
    }
  }
}

// --------------------------- kernel 2: flash attention ----------------------
// 256 blocks: bid = ((batch*16+qt)<<2)|split -> 1 block/CU exactly.
// Block = 4 waves * 64 q = 256 q; kv = split*1024..+1024 (32 tiles of 32).
// 3-buffer LDS (36KB), stage distance 2; region:
//   {s_waitcnt vmcnt(3); s_barrier; stage(t+2); QK(t)+SM(t)+PV(t)}
__global__ __launch_bounds__(256, 2) void attn_kernel(char* __restrict__ ws) {
  int bid = blockIdx.x;
  int split = bid & 3;
  int qt = (bid >> 2) & 15;
  int batch = bid >> 6;
  int tid = threadIdx.x;
  int wid = tid >> 6, lane = tid & 63, l31 = lane & 31, hi = lane >> 5;

  const char* Qb  = ws + Q_OFF  + (size_t)batch * (4096 * 128);
  const char* Kt0 = ws + KF_OFF + (size_t)batch * (512 << 10) +
                    (size_t)(split * 32) * 4096;
  const char* Vt0 = ws + VF_OFF + (size_t)batch * (1u << 20) +
                    (size_t)(split * 32) * 8192;

  __shared__ char sbuf[3][12288];       // [0,4K)=K tile, [4K,12K)=V tile

  int q0 = qt * 256 + wid * 64;
  int lo16 = lane * 16;

  bf16x8 qf0[4], qf1[4];                // Q frags for the wave's 2 q-sets
#pragma unroll
  for (int d0 = 0; d0 < 4; ++d0) {
    qf0[d0] = *(const bf16x8*)(Qb + (size_t)(q0 + l31) * 128 + d0 * 32 + hi * 16);
    qf1[d0] = *(const bf16x8*)(Qb + (size_t)(q0 + 32 + l31) * 128 + d0 * 32 + hi * 16);
  }

  f32x16 oacc[2][4];
#pragma unroll
  for (int qs = 0; qs < 2; ++qs)
#pragma unroll
    for (int i = 0; i < 4; ++i) oacc[qs][i] = 0.f;
  float denA0 = 0.f, denA1 = 0.f, denB0 = 0.f, denB1 = 0.f;

  // each wave stages 3 of the 12 1KB chunks (K: c<4, V: c>=4)
  auto stage = [&](int b, int t) {
#pragma unroll
    for (int i = 0; i < 3; ++i) {
      int c = wid * 3 + i;
      const char* src = (c < 4) ? Kt0 + (size_t)t * 4096 + c * 1024 + lo16
                                : Vt0 + (size_t)t * 8192 + (c - 4) * 1024 + lo16;
      gld_lds16(src, &sbuf[b][c * 1024]);
    }
  };

  stage(0, 0);                          // 3 outstanding (this wave)
  stage(1, 1);                          // 6 outstanding

  for (int t = 0; t < 32; ++t) {
    // wait ONLY for tile t's 3 loads (issued 2 regions ago); t+1's in flight
    if (t < 31) asm volatile("s_waitcnt vmcnt(3)" ::: "memory");
    else        asm volatile("s_waitcnt vmcnt(0)" ::: "memory");
    __builtin_amdgcn_s_barrier();       // raw: no drain; all waves' chunks in

    if (t + 2 < 32) stage((t + 2) % 3, t + 2);   // overlaps this region

    const char* kb = sbuf[t % 3];
    const char* vb = kb + 4096;

    // QK both q-sets: S^T[k][q], k = (reg&3)+8*(reg>>2)+4*hi, q = l31
    f32x16 s0, s1;
    s0 = 0.f; s1 = 0.f;
#pragma unroll
    for (int d0 = 0; d0 < 4; ++d0) {
      bf16x8 kf = *(const bf16x8*)(kb + d0 * 1024 + lo16);
      s0 = __builtin_amdgcn_mfma_f32_32x32x16_bf16(kf, qf0[d0], s0, 0, 0, 0);
      s1 = __builtin_amdgcn_mfma_f32_32x32x16_bf16(kf, qf1[d0], s1, 0, 0, 0);
    }

    // softmax: p = exp2(s) (Q pre-scaled by log2e), unnormalized
    unsigned pk0[8], pk1[8];
#pragma unroll
    for (int m = 0; m < 8; ++m) {
      float a0 = __builtin_amdgcn_exp2f(s0[2 * m]);
      float a1 = __builtin_amdgcn_exp2f(s0[2 * m + 1]);
      if (m & 1) denA1 += a0 + a1; else denA0 += a0 + a1;
      pk0[m] = pack2(a0, a1);
      float b0 = __builtin_amdgcn_exp2f(s1[2 * m]);
      float b1 = __builtin_amdgcn_exp2f(s1[2 * m + 1]);
      if (m & 1) denB1 += b0 + b1; else denB0 += b0 + b1;
      pk1[m] = pack2(b0, b1);
    }

    // PV: O^T[dv][q] += V^T · P^T ; each vf read feeds both q-sets
#pragma unroll
    for (int kc = 0; kc < 2; ++kc) {
      const int bs = kc * 4;
      u32x2 r0 = __builtin_amdgcn_permlane32_swap(pk0[bs + 0], pk0[bs + 2],
                                                  false, false);
      u32x2 r1 = __builtin_amdgcn_permlane32_swap(pk0[bs + 1], pk0[bs + 3],
                                                  false, false);
      u32x4 pu0 = {r0.x, r1.x, r0.y, r1.y};
      bf16x8 pf0 = __builtin_bit_cast(bf16x8, pu0);
      u32x2 r2 = __builtin_amdgcn_permlane32_swap(pk1[bs + 0], pk1[bs + 2],
                                                  false, false);
      u32x2 r3 = __builtin_amdgcn_permlane32_swap(pk1[bs + 1], pk1[bs + 3],
                                                  false, false);
      u32x4 pu1 = {r2.x, r3.x, r2.y, r3.y};
      bf16x8 pf1 = __builtin_bit_cast(bf16x8, pu1);
#pragma unroll
      for (int dvb = 0; dvb < 4; ++dvb) {
        bf16x8 vf = *(const bf16x8*)(vb + (dvb * 2 + kc) * 1024 + lo16);
        oacc[0][dvb] = __builtin_amdgcn_mfma_f32_32x32x16_bf16(vf, pf0,
                                                               oacc[0][dvb], 0, 0, 0);
        oacc[1][dvb] = __builtin_amdgcn_mfma_f32_32x32x16_bf16(vf, pf1,
                                                               oacc[1][dvb], 0, 0, 0);
      }
    }
    // no trailing barrier: next region's top barrier provides WAR safety
  }

  // write numerator partials (bf16, cacheable -> L2/L3 for combine) + den
  unsigned short* OPu = (unsigned short*)(ws + OP_OFF) +
                        (size_t)((batch * 16 + qt) * 4 + split) * 32768;
#pragma unroll
  for (int qs = 0; qs < 2; ++qs) {
    int qloc = wid * 64 + qs * 32 + l31;
#pragma unroll
    for (int dvb = 0; dvb < 4; ++dvb)
#pragma unroll
      for (int reg = 0; reg < 16; ++reg) {
        int dv = dvb * 32 + (reg & 3) + 8 * (reg >> 2) + 4 * hi;
        OPu[dv * 256 + qloc] = f2bf(oacc[qs][dvb][reg]);
      }
    float den = qs ? (denB0 + denB1) : (denA0 + denA1);
    float dtot = den + __shfl_xor(den, 32, 64);
    if (hi == 0) {
      float* DEN = (float*)(ws + DEN_OFF) +
                   (size_t)((batch * 16 + qt) * 4 + split) * 256;
      DEN[qloc] = dtot;
    }
  }
}

// --------------------------- kernel 3: combine splits -----------------------
// 1024 blocks; each thread produces 8 consecutive outputs (vectorized loads).
__global__ __launch_bounds__(256) void combine_kernel(const char* __restrict__ ws,
                                                      float* __restrict__ out) {
  int idx8 = (blockIdx.x * 256 + threadIdx.x) * 8;  // 2^21 outputs [n][c][s]
  int n = idx8 >> 19;
  int dv = (idx8 >> 12) & 127;
  int s0 = idx8 & 4095;                 // 8-aligned
  int qt = s0 >> 8, ql = s0 & 255;
  const unsigned short* OPu = (const unsigned short*)(ws + OP_OFF);
  const float* DEN = (const float*)(ws + DEN_OFF);
  size_t pb = (size_t)((n * 16 + qt) * 4);
  float num[8], den[8];
#pragma unroll
  for (int j = 0; j < 8; ++j) { num[j] = 0.f; den[j] = 0.f; }
#pragma unroll
  for (int h = 0; h < 4; ++h) {
    bf16x8 v = *(const bf16x8*)(OPu + (pb + h) * 32768 + (size_t)dv * 256 + ql);
    const float* dp = DEN + (pb + h) * 256 + ql;
    float4 d0 = *(const float4*)dp;
    float4 d1 = *(const float4*)(dp + 4);
#pragma unroll
    for (int j = 0; j < 8; ++j) num[j] += (float)v[j];
    den[0] += d0.x; den[1] += d0.y; den[2] += d0.z; den[3] += d0.w;
    den[4] += d1.x; den[5] += d1.y; den[6] += d1.z; den[7] += d1.w;
  }
  float4 o0 = {num[0] / den[0], num[1] / den[1], num[2] / den[2], num[3] / den[3]};
  float4 o1 = {num[4] / den[4], num[5] / den[5], num[6] / den[6], num[7] / den[7]};
  *(float4*)&out[idx8] = o0;
  *(float4*)&out[idx8 + 4] = o1;
}

// ---------------------------------------------------------------------------
extern "C" void kernel_launch(void* const* d_in, const int* in_sizes, int n_in,
                              void* d_out, int out_size, void* d_ws, size_t ws_size,
                              hipStream_t stream) {
  (void)in_sizes; (void)n_in; (void)out_size; (void)ws_size;
  const float* x  = (const float*)d_in[0];
  const float* w1 = (const float*)d_in[1];
  const float* b1 = (const float*)d_in[2];
  const float* a1 = (const float*)d_in[3];
  const float* w2 = (const float*)d_in[4];
  const float* b2 = (const float*)d_in[5];
  const float* a2 = (const float*)d_in[6];
  const float* wa = (const float*)d_in[7];
  const float* ba = (const float*)d_in[8];
  const float* aa = (const float*)d_in[9];
  char* ws = (char*)d_ws;
  float* out = (float*)d_out;

  wcast_kernel<<<dim3(32), dim3(256), 0, stream>>>(w1, w2, wa, ws);
  conv_kernel<<<dim3(512), dim3(256), 0, stream>>>(x, ws, b1, a1, b2, a2, ba, aa);
  attn_kernel<<<dim3(256), dim3(256), 0, stream>>>(ws);
  combine_kernel<<<dim3(1024), dim3(256), 0, stream>>>(ws, out);
}